// Round 12
// baseline (279.461 us; speedup 1.0000x reference)
//
#include <hip/hip_runtime.h>

#define BB 32
#define TT 512
#define FF 128
#define HID 256
#define TP 1024

typedef __attribute__((ext_vector_type(8))) short s16x8;
typedef __attribute__((ext_vector_type(8))) unsigned short u16x8;
typedef __attribute__((ext_vector_type(4))) unsigned short u16x4;
typedef __attribute__((ext_vector_type(4))) float f32x4;

static __device__ __forceinline__ unsigned short f2bf(float f) {
    unsigned u = __builtin_bit_cast(unsigned, f);
    u = (u + 0x7FFFu + ((u >> 16) & 1u)) >> 16;
    return (unsigned short)u;
}
static __device__ __forceinline__ float bf2f(unsigned short b) {
    return __builtin_bit_cast(float, ((unsigned)b) << 16);
}

// ---------------------------------------------------------------------------
// qkv weight prep only: out bf16 [6][128][128]; planes 0,3 pre-scaled.
// grid (384), block 256.
// ---------------------------------------------------------------------------
__global__ __launch_bounds__(256) void prep_qkvw_kernel(
    const float* __restrict__ wqa, const float* __restrict__ wka,
    const float* __restrict__ wva, const float* __restrict__ wqb,
    const float* __restrict__ wkb, const float* __restrict__ wvb,
    unsigned short* __restrict__ qkvw)
{
    int idx = blockIdx.x * 256 + threadIdx.x;
    if (idx >= 98304) return;
    int p = idx >> 14, rc = idx & 16383;
    const float* srcs[6] = {wqa, wka, wva, wqb, wkb, wvb};
    float v = srcs[p][rc];
    if (p == 0 || p == 3) v *= 0.088388347648318447f;
    qkvw[idx] = f2bf(v);
}

// tcn weight prep helper: w4[plane][o][c] bf16, planes 0..2 conv, 3 residual
static __device__ __forceinline__ void tcnw_prep(
    int idx, const float* __restrict__ cw, const float* __restrict__ rw,
    unsigned short* __restrict__ out, int Cin)
{
    int p = idx / (256 * Cin);
    int rem = idx - p * 256 * Cin;
    int o = rem / Cin, c = rem - o * Cin;
    float v = (p < 3) ? cw[(o * Cin + c) * 3 + p] : rw[o * Cin + c];
    out[idx] = f2bf(v);
}

// ---------------------------------------------------------------------------
// QKV projection via MFMA, 64-row t-tiles.  x source modes:
//   mode 0: fp32 [b][128][512] (c-major);  mode 1: bf16 [b][t][128] (t-major)
// grid (8, 32), block 256 = 4 waves.
// ---------------------------------------------------------------------------
__global__ __launch_bounds__(256) void proj_mfma_kernel(
    const void* __restrict__ xq_src, int xq_mode, long long xq_bs,
    const void* __restrict__ xkv_src, int xkv_mode, long long xkv_bs,
    const unsigned short* __restrict__ w3,
    const float* __restrict__ bq, const float* __restrict__ bk,
    const float* __restrict__ bv,
    unsigned short* __restrict__ Qo, unsigned short* __restrict__ Ko,
    unsigned short* __restrict__ Vt)
{
    int t0 = blockIdx.x * 64, b = blockIdx.y;
    __shared__ __align__(16) unsigned short xsq[64 * 136];
    __shared__ __align__(16) unsigned short xskv[64 * 136];
    int tid = threadIdx.x;
    int wid = tid >> 6, lane = tid & 63;
    int n = lane & 15, g = lane >> 4;
    int tsub = (wid & 1) * 16, fh = (wid >> 1) * 64;

    if (xq_mode == 0) {
        const float* s = (const float*)xq_src + (size_t)b * xq_bs;
        for (int l = tid; l < 8192; l += 256) {
            int c = l >> 6, tt = l & 63;
            xsq[tt * 136 + c] = f2bf(s[(size_t)c * TT + t0 + tt]);
        }
    } else {
        const unsigned short* s = (const unsigned short*)xq_src + (size_t)b * xq_bs;
        for (int l = tid; l < 1024; l += 256) {
            int r = l >> 4, cc = l & 15;
            *(u16x8*)&xsq[r * 136 + cc * 8] = *(const u16x8*)&s[(size_t)(t0 + r) * FF + cc * 8];
        }
    }
    if (xkv_mode == 0) {
        const float* s = (const float*)xkv_src + (size_t)b * xkv_bs;
        for (int l = tid; l < 8192; l += 256) {
            int c = l >> 6, tt = l & 63;
            xskv[tt * 136 + c] = f2bf(s[(size_t)c * TT + t0 + tt]);
        }
    } else {
        const unsigned short* s = (const unsigned short*)xkv_src + (size_t)b * xkv_bs;
        for (int l = tid; l < 1024; l += 256) {
            int r = l >> 4, cc = l & 15;
            *(u16x8*)&xskv[r * 136 + cc * 8] = *(const u16x8*)&s[(size_t)(t0 + r) * FF + cc * 8];
        }
    }
    __syncthreads();

    f32x4 acc[2][3][4];
#pragma unroll
    for (int tt = 0; tt < 2; ++tt)
#pragma unroll
        for (int p = 0; p < 3; ++p)
#pragma unroll
            for (int i = 0; i < 4; ++i) acc[tt][p][i] = (f32x4){0.f, 0.f, 0.f, 0.f};

#pragma unroll
    for (int kk = 0; kk < 4; ++kk) {
        s16x8 bxq0 = *(const s16x8*)&xsq[(tsub + n) * 136 + kk * 32 + g * 8];
        s16x8 bxq1 = *(const s16x8*)&xsq[(32 + tsub + n) * 136 + kk * 32 + g * 8];
        s16x8 bxk0 = *(const s16x8*)&xskv[(tsub + n) * 136 + kk * 32 + g * 8];
        s16x8 bxk1 = *(const s16x8*)&xskv[(32 + tsub + n) * 136 + kk * 32 + g * 8];
#pragma unroll
        for (int i = 0; i < 4; ++i) {
            const unsigned short* wb = &w3[(size_t)(fh + i * 16 + n) * 128 + kk * 32 + g * 8];
            s16x8 a0 = *(const s16x8*)&wb[0];
            s16x8 a1 = *(const s16x8*)&wb[16384];
            s16x8 a2 = *(const s16x8*)&wb[32768];
            acc[0][0][i] = __builtin_amdgcn_mfma_f32_16x16x32_bf16(a0, bxq0, acc[0][0][i], 0, 0, 0);
            acc[0][1][i] = __builtin_amdgcn_mfma_f32_16x16x32_bf16(a1, bxk0, acc[0][1][i], 0, 0, 0);
            acc[0][2][i] = __builtin_amdgcn_mfma_f32_16x16x32_bf16(a2, bxk0, acc[0][2][i], 0, 0, 0);
            acc[1][0][i] = __builtin_amdgcn_mfma_f32_16x16x32_bf16(a0, bxq1, acc[1][0][i], 0, 0, 0);
            acc[1][1][i] = __builtin_amdgcn_mfma_f32_16x16x32_bf16(a1, bxk1, acc[1][1][i], 0, 0, 0);
            acc[1][2][i] = __builtin_amdgcn_mfma_f32_16x16x32_bf16(a2, bxk1, acc[1][2][i], 0, 0, 0);
        }
    }

    const float scale = 0.088388347648318447f;
#pragma unroll
    for (int tt = 0; tt < 2; ++tt) {
        int t = t0 + tt * 32 + tsub + n;
#pragma unroll
        for (int i = 0; i < 4; ++i) {
            int fb = fh + i * 16 + g * 4;
            u16x4 pk;
#pragma unroll
            for (int r = 0; r < 4; ++r) pk[r] = f2bf(acc[tt][0][i][r] + bq[fb + r] * scale);
            *(u16x4*)&Qo[((size_t)b * TT + t) * FF + fb] = pk;
#pragma unroll
            for (int r = 0; r < 4; ++r) pk[r] = f2bf(acc[tt][1][i][r] + bk[fb + r]);
            *(u16x4*)&Ko[((size_t)b * TT + t) * FF + fb] = pk;
#pragma unroll
            for (int r = 0; r < 4; ++r)
                Vt[((size_t)b * FF + fb + r) * TT + t] = f2bf(acc[tt][2][i][r] + bv[fb + r]);
        }
    }
}

// ---------------------------------------------------------------------------
// Flash attention via MFMA.  grid (8, 32) [A] or (8, 33) [B: y==32 plane does
// tcn weight prep].  block 256 = 4 waves.
// ---------------------------------------------------------------------------
__global__ __launch_bounds__(256) void attn_mfma_kernel(
    const unsigned short* __restrict__ Qb, const unsigned short* __restrict__ Kb,
    const unsigned short* __restrict__ Vtb,
    const float* __restrict__ orig, long long bso, int cso, int tso,
    float* __restrict__ out_tf, unsigned short* __restrict__ out_x, int xoff,
    const float* __restrict__ cw0, const float* __restrict__ rw0,
    const float* __restrict__ cw1, const float* __restrict__ rw1,
    const float* __restrict__ cw2, const float* __restrict__ rw2,
    unsigned short* __restrict__ wb0, unsigned short* __restrict__ wb1,
    unsigned short* __restrict__ wb2)
{
    __shared__ __align__(16) unsigned short Ks[64 * 136];
    __shared__ __align__(16) unsigned short Vs[128 * 72];
    __shared__ __align__(16) unsigned short Ps[4 * 16 * 68];

    int tid = threadIdx.x;
    if (blockIdx.y == 32) {
        // tcn weight prep rides in attn-B's launch (8 blocks, grid-stride)
        int idx0 = blockIdx.x * 256 + tid;
        for (int idx = idx0; idx < 655360; idx += 2048) {
            if (idx < 131072) tcnw_prep(idx, cw0, rw0, wb0, 128);
            else if (idx < 393216) tcnw_prep(idx - 131072, cw1, rw1, wb1, 256);
            else tcnw_prep(idx - 393216, cw2, rw2, wb2, 256);
        }
        return;
    }

    int t0 = blockIdx.x * 64, b = blockIdx.y;
    int wid = tid >> 6, lane = tid & 63;
    int n = lane & 15, g = lane >> 4;
    int q0 = t0 + wid * 16;
    unsigned short* Pw = &Ps[wid * 1088];

    s16x8 qf[4];
#pragma unroll
    for (int kk = 0; kk < 4; ++kk)
        qf[kk] = *(const s16x8*)&Qb[((size_t)b * TT + q0 + n) * FF + kk * 32 + g * 8];

    u16x8 kst[4], vst[4];
#pragma unroll
    for (int ii = 0; ii < 4; ++ii) {
        int l = tid + 256 * ii;
        kst[ii] = *(const u16x8*)&Kb[((size_t)b * TT + (l >> 4)) * FF + (l & 15) * 8];
        vst[ii] = *(const u16x8*)&Vtb[((size_t)b * FF + (l >> 3)) * TT + (l & 7) * 8];
    }

    f32x4 O[8];
#pragma unroll
    for (int ft = 0; ft < 8; ++ft) O[ft] = (f32x4){0.f, 0.f, 0.f, 0.f};
    float m[4] = {-1e30f, -1e30f, -1e30f, -1e30f};
    float lsum[4] = {0.f, 0.f, 0.f, 0.f};

    for (int it = 0; it < 8; ++it) {
        __syncthreads();
#pragma unroll
        for (int ii = 0; ii < 4; ++ii) {
            int l = tid + 256 * ii;
            *(u16x8*)&Ks[(l >> 4) * 136 + (l & 15) * 8] = kst[ii];
            *(u16x8*)&Vs[(l >> 3) * 72 + (l & 7) * 8] = vst[ii];
        }
        __syncthreads();
        if (it < 7) {
            int s0n = (it + 1) * 64;
#pragma unroll
            for (int ii = 0; ii < 4; ++ii) {
                int l = tid + 256 * ii;
                kst[ii] = *(const u16x8*)&Kb[((size_t)b * TT + s0n + (l >> 4)) * FF + (l & 15) * 8];
                vst[ii] = *(const u16x8*)&Vtb[((size_t)b * FF + (l >> 3)) * TT + s0n + (l & 7) * 8];
            }
        }

        f32x4 acc[4];
#pragma unroll
        for (int st = 0; st < 4; ++st) acc[st] = (f32x4){0.f, 0.f, 0.f, 0.f};
        __builtin_amdgcn_s_setprio(1);
#pragma unroll
        for (int kk = 0; kk < 4; ++kk) {
#pragma unroll
            for (int st = 0; st < 4; ++st) {
                s16x8 kf = *(const s16x8*)&Ks[(st * 16 + n) * 136 + kk * 32 + g * 8];
                acc[st] = __builtin_amdgcn_mfma_f32_16x16x32_bf16(qf[kk], kf, acc[st], 0, 0, 0);
            }
        }
        __builtin_amdgcn_s_setprio(0);

        float mnew[4], c[4], rs[4];
#pragma unroll
        for (int r = 0; r < 4; ++r) {
            float tm = fmaxf(fmaxf(acc[0][r], acc[1][r]), fmaxf(acc[2][r], acc[3][r]));
#pragma unroll
            for (int msk = 1; msk < 16; msk <<= 1) tm = fmaxf(tm, __shfl_xor(tm, msk));
            mnew[r] = fmaxf(m[r], tm);
            c[r] = __expf(m[r] - mnew[r]);
            m[r] = mnew[r];
            rs[r] = 0.f;
        }
#pragma unroll
        for (int st = 0; st < 4; ++st) {
#pragma unroll
            for (int r = 0; r < 4; ++r) {
                float p = __expf(acc[st][r] - mnew[r]);
                rs[r] += p;
                Pw[(g * 4 + r) * 68 + st * 16 + n] = f2bf(p);
            }
        }
#pragma unroll
        for (int r = 0; r < 4; ++r) {
#pragma unroll
            for (int msk = 1; msk < 16; msk <<= 1) rs[r] += __shfl_xor(rs[r], msk);
            lsum[r] = lsum[r] * c[r] + rs[r];
        }
#pragma unroll
        for (int ft = 0; ft < 8; ++ft) {
#pragma unroll
            for (int r = 0; r < 4; ++r) O[ft][r] *= c[r];
        }

        __builtin_amdgcn_s_setprio(1);
#pragma unroll
        for (int ks = 0; ks < 2; ++ks) {
            s16x8 pf = *(const s16x8*)&Pw[n * 68 + ks * 32 + g * 8];
#pragma unroll
            for (int ft = 0; ft < 8; ++ft) {
                s16x8 vf = *(const s16x8*)&Vs[(ft * 16 + n) * 72 + ks * 32 + g * 8];
                O[ft] = __builtin_amdgcn_mfma_f32_16x16x32_bf16(pf, vf, O[ft], 0, 0, 0);
            }
        }
        __builtin_amdgcn_s_setprio(0);
    }

    float rinv[4];
#pragma unroll
    for (int r = 0; r < 4; ++r) rinv[r] = 1.f / lsum[r];
#pragma unroll
    for (int ft = 0; ft < 8; ++ft) {
        int f = ft * 16 + n;
#pragma unroll
        for (int r = 0; r < 4; ++r) {
            int q = q0 + g * 4 + r;
            float val = O[ft][r] * rinv[r];
            float xv = orig[bso * b + (size_t)f * cso + (size_t)q * tso];
            float res = val * xv + xv;
            out_tf[((size_t)b * TT + q) * FF + f] = res;
            out_x[((size_t)b * TP + xoff + q) * FF + f] = f2bf(res);
        }
    }
}

// ---------------------------------------------------------------------------
// TCN layer via MFMA (R11 proven structure), with optional merged-MMD plane.
// grid (4, 4, 32) normally; L1 uses (4, 5, 32) + do_mmd=1: blocks y==4 run
// the MMD Gram path (128 blocks x 4 timepoints), overlapping TCN L1.
// MMD LDS overlays the tcn smem union: X arrays (34.8 KB) during compute;
// Gs+red (13.7 KB) overlay X after a barrier (accs held in registers).
// ---------------------------------------------------------------------------
__global__ __launch_bounds__(256, 2) void tcn_mfma_kernel(
    const unsigned short* __restrict__ x, int Cin, int d,
    const unsigned short* __restrict__ w4,
    const float* __restrict__ cb, const float* __restrict__ rb,
    unsigned short* __restrict__ out, float* __restrict__ pool_out, int do_pool,
    const float* __restrict__ f1, const float* __restrict__ f2,
    float* __restrict__ partials, int do_mmd)
{
    __shared__ __align__(16) unsigned short smem[20800];
    __shared__ float pool_s[4][64];
    int tid = threadIdx.x;

    if (do_mmd && blockIdx.y == 4) {
        // ------------------- MMD path (merged) -------------------
        unsigned short* X1h = smem;
        unsigned short* X1l = smem + 4352;
        unsigned short* X2h = smem + 8704;
        unsigned short* X2l = smem + 13056;
        float* Gsf = (float*)smem;        // overlay after X reads complete
        float* red = Gsf + 3168;          // 3*32*33 floats, then 256 floats
        int wid2 = tid >> 6, lane = tid & 63;
        int n = lane & 15, g = lane >> 4;
        int tb = (blockIdx.z * 4 + blockIdx.x) * 4;
        for (int k4 = 0; k4 < 4; ++k4) {
            int t = tb + k4;
            __syncthreads();   // protect prior iter's Gs/red reads
            for (int l = tid; l < 4096; l += 256) {
                int i = l >> 7, f = l & 127;
                float v1 = f1[((size_t)i * TT + t) * FF + f];
                float v2 = f2[((size_t)i * TT + t) * FF + f];
                unsigned short h1 = f2bf(v1);
                unsigned short h2 = f2bf(v2);
                X1h[i * 136 + f] = h1;
                X1l[i * 136 + f] = f2bf(v1 - bf2f(h1));
                X2h[i * 136 + f] = h2;
                X2l[i * 136 + f] = f2bf(v2 - bf2f(h2));
            }
            __syncthreads();
            f32x4 accu[3];
#pragma unroll
            for (int uu = 0; uu < 3; ++uu) {
                int u = wid2 * 3 + uu;
                int gram = u >> 2, quad = u & 3;
                int qi = quad >> 1, qj = quad & 1;
                const unsigned short* Ah = (gram == 1) ? X2h : X1h;
                const unsigned short* Al = (gram == 1) ? X2l : X1l;
                const unsigned short* Bh = (gram == 0) ? X1h : X2h;
                const unsigned short* Bl = (gram == 0) ? X1l : X2l;
                f32x4 acc = (f32x4){0.f, 0.f, 0.f, 0.f};
#pragma unroll
                for (int kk = 0; kk < 4; ++kk) {
                    int ao = (qi * 16 + n) * 136 + kk * 32 + g * 8;
                    int bo = (qj * 16 + n) * 136 + kk * 32 + g * 8;
                    s16x8 ah = *(const s16x8*)&Ah[ao];
                    s16x8 al = *(const s16x8*)&Al[ao];
                    s16x8 bh = *(const s16x8*)&Bh[bo];
                    s16x8 bl = *(const s16x8*)&Bl[bo];
                    acc = __builtin_amdgcn_mfma_f32_16x16x32_bf16(ah, bh, acc, 0, 0, 0);
                    acc = __builtin_amdgcn_mfma_f32_16x16x32_bf16(ah, bl, acc, 0, 0, 0);
                    acc = __builtin_amdgcn_mfma_f32_16x16x32_bf16(al, bh, acc, 0, 0, 0);
                }
                accu[uu] = acc;
            }
            __syncthreads();   // all X reads done; safe to overlay with Gs
#pragma unroll
            for (int uu = 0; uu < 3; ++uu) {
                int u = wid2 * 3 + uu;
                int gram = u >> 2, quad = u & 3;
                int qi = quad >> 1, qj = quad & 1;
#pragma unroll
                for (int r = 0; r < 4; ++r)
                    Gsf[gram * 1056 + (qi * 16 + g * 4 + r) * 33 + qj * 16 + n] = accu[uu][r];
            }
            __syncthreads();
            float s = 0.f;
#pragma unroll
            for (int r = 0; r < 4; ++r) {
                int p = tid + 256 * r;
                int i = p >> 5, j = p & 31;
                float g11 = Gsf[i * 33 + i], g1jj = Gsf[j * 33 + j];
                float g22 = Gsf[1056 + i * 33 + i], g2jj = Gsf[1056 + j * 33 + j];
                float d11 = g11 + g1jj - 2.f * Gsf[i * 33 + j];
                float d22 = g22 + g2jj - 2.f * Gsf[1056 + i * 33 + j];
                float d12 = g11 + g2jj - 2.f * Gsf[2112 + i * 33 + j];
                s += __expf(-0.5f * d11) + __expf(-0.5f * d22) - 2.f * __expf(-0.5f * d12);
            }
            red[tid] = s;
            __syncthreads();
            for (int off = 128; off; off >>= 1) {
                if (tid < off) red[tid] += red[tid + off];
                __syncthreads();
            }
            if (tid == 0) partials[t] = red[0];
        }
        return;
    }

    // ------------------- TCN path (R11 verbatim) -------------------
    int t0 = blockIdx.x * 256, o0 = blockIdx.y * 64, b = blockIdx.z;
    unsigned short* xs = smem;
    unsigned short* wsh = smem + 10560;
    int wid = tid >> 6, lane = tid & 63;
    int n = lane & 15, g = lane >> 4;
    int wt = wid * 64;
    int d2 = 2 * d;
    const unsigned short* xb = x + (size_t)b * TP * Cin;

    int gg = tid & 3;
    int xr0 = tid >> 2;
    int tg0 = t0 - d2 + xr0;
    bool xv4 = xr0 < d2;
    const unsigned short* wbase = w4 + (size_t)(o0 + (tid >> 2)) * Cin + gg * 8;
    size_t wps = (size_t)256 * Cin;

    u16x8 sx0, sx1, sx2, sx3, sx4, sw0, sw1, sw2, sw3;
    const u16x8 zz = {0, 0, 0, 0, 0, 0, 0, 0};
#define LDST(C0)                                                               \
    do {                                                                       \
        sx0 = (tg0 >= 0) ? *(const u16x8*)&xb[(size_t)tg0 * Cin + (C0) + gg * 8] : zz; \
        sx1 = *(const u16x8*)&xb[(size_t)(tg0 + 64) * Cin + (C0) + gg * 8];    \
        sx2 = *(const u16x8*)&xb[(size_t)(tg0 + 128) * Cin + (C0) + gg * 8];   \
        sx3 = *(const u16x8*)&xb[(size_t)(tg0 + 192) * Cin + (C0) + gg * 8];   \
        sx4 = xv4 ? *(const u16x8*)&xb[(size_t)(tg0 + 256) * Cin + (C0) + gg * 8] : zz; \
        sw0 = *(const u16x8*)&wbase[(C0)];                                     \
        sw1 = *(const u16x8*)&wbase[wps + (C0)];                               \
        sw2 = *(const u16x8*)&wbase[2 * wps + (C0)];                           \
        sw3 = *(const u16x8*)&wbase[3 * wps + (C0)];                           \
    } while (0)

    f32x4 accc[4][4], accr[4][4];
#pragma unroll
    for (int i = 0; i < 4; ++i)
#pragma unroll
        for (int j = 0; j < 4; ++j) {
            accc[i][j] = (f32x4){0.f, 0.f, 0.f, 0.f};
            accr[i][j] = (f32x4){0.f, 0.f, 0.f, 0.f};
        }

    LDST(0);
    for (int c0 = 0; c0 < Cin; c0 += 32) {
        __syncthreads();
        *(u16x8*)&xs[xr0 * 40 + gg * 8] = sx0;
        *(u16x8*)&xs[(xr0 + 64) * 40 + gg * 8] = sx1;
        *(u16x8*)&xs[(xr0 + 128) * 40 + gg * 8] = sx2;
        *(u16x8*)&xs[(xr0 + 192) * 40 + gg * 8] = sx3;
        if (xv4) *(u16x8*)&xs[(xr0 + 256) * 40 + gg * 8] = sx4;
        {
            int wrow = (tid >> 2) * 40 + gg * 8;
            *(u16x8*)&wsh[wrow] = sw0;
            *(u16x8*)&wsh[2560 + wrow] = sw1;
            *(u16x8*)&wsh[5120 + wrow] = sw2;
            *(u16x8*)&wsh[7680 + wrow] = sw3;
        }
        __syncthreads();
        if (c0 + 32 < Cin) LDST(c0 + 32);

        s16x8 bfr[4][3];
#pragma unroll
        for (int j = 0; j < 4; ++j) {
            int tl = wt + j * 16 + n;
#pragma unroll
            for (int k = 0; k < 3; ++k)
                bfr[j][k] = *(const s16x8*)&xs[(tl + k * d) * 40 + g * 8];
        }
        __builtin_amdgcn_s_setprio(1);
#pragma unroll
        for (int i = 0; i < 4; ++i) {
            int wrow = (i * 16 + n) * 40 + g * 8;
            s16x8 a0 = *(const s16x8*)&wsh[wrow];
            s16x8 a1 = *(const s16x8*)&wsh[2560 + wrow];
            s16x8 a2 = *(const s16x8*)&wsh[5120 + wrow];
            s16x8 ar = *(const s16x8*)&wsh[7680 + wrow];
#pragma unroll
            for (int j = 0; j < 4; ++j) {
                accc[i][j] = __builtin_amdgcn_mfma_f32_16x16x32_bf16(a0, bfr[j][0], accc[i][j], 0, 0, 0);
                accc[i][j] = __builtin_amdgcn_mfma_f32_16x16x32_bf16(a1, bfr[j][1], accc[i][j], 0, 0, 0);
                accc[i][j] = __builtin_amdgcn_mfma_f32_16x16x32_bf16(a2, bfr[j][2], accc[i][j], 0, 0, 0);
                accr[i][j] = __builtin_amdgcn_mfma_f32_16x16x32_bf16(ar, bfr[j][2], accr[i][j], 0, 0, 0);
            }
        }
        __builtin_amdgcn_s_setprio(0);
    }
#undef LDST

    if (!do_pool) {
        __syncthreads();
        unsigned short* ot = smem;
#pragma unroll
        for (int i = 0; i < 4; ++i) {
            int ob = o0 + i * 16 + g * 4;
            float cbv0 = cb[ob], cbv1 = cb[ob + 1], cbv2 = cb[ob + 2], cbv3 = cb[ob + 3];
            float rbv0 = rb[ob], rbv1 = rb[ob + 1], rbv2 = rb[ob + 2], rbv3 = rb[ob + 3];
#pragma unroll
            for (int j = 0; j < 4; ++j) {
                int tl = wt + j * 16 + n;
                u16x4 pk;
                pk[0] = f2bf(fmaxf(accc[i][j][0] + cbv0, 0.f) + accr[i][j][0] + rbv0);
                pk[1] = f2bf(fmaxf(accc[i][j][1] + cbv1, 0.f) + accr[i][j][1] + rbv1);
                pk[2] = f2bf(fmaxf(accc[i][j][2] + cbv2, 0.f) + accr[i][j][2] + rbv2);
                pk[3] = f2bf(fmaxf(accc[i][j][3] + cbv3, 0.f) + accr[i][j][3] + rbv3);
                *(u16x4*)&ot[tl * 66 + i * 16 + g * 4] = pk;
            }
        }
        __syncthreads();
        int tl = tid >> 3, c8 = tid & 7;
#pragma unroll
        for (int s = 0; s < 8; ++s) {
            int trow = tl + 32 * s;
            *(u16x8*)&out[((size_t)b * TP + t0 + trow) * HID + o0 + c8 * 8] =
                *(const u16x8*)&ot[trow * 66 + c8 * 8];
        }
    } else {
#pragma unroll
        for (int i = 0; i < 4; ++i) {
            int ob = o0 + i * 16 + g * 4;
            float cbv0 = cb[ob], cbv1 = cb[ob + 1], cbv2 = cb[ob + 2], cbv3 = cb[ob + 3];
            float rbv0 = rb[ob], rbv1 = rb[ob + 1], rbv2 = rb[ob + 2], rbv3 = rb[ob + 3];
            float ps0 = 0.f, ps1 = 0.f, ps2 = 0.f, ps3 = 0.f;
#pragma unroll
            for (int j = 0; j < 4; ++j) {
                ps0 += fmaxf(accc[i][j][0] + cbv0, 0.f) + accr[i][j][0] + rbv0;
                ps1 += fmaxf(accc[i][j][1] + cbv1, 0.f) + accr[i][j][1] + rbv1;
                ps2 += fmaxf(accc[i][j][2] + cbv2, 0.f) + accr[i][j][2] + rbv2;
                ps3 += fmaxf(accc[i][j][3] + cbv3, 0.f) + accr[i][j][3] + rbv3;
            }
#pragma unroll
            for (int msk = 1; msk < 16; msk <<= 1) {
                ps0 += __shfl_xor(ps0, msk);
                ps1 += __shfl_xor(ps1, msk);
                ps2 += __shfl_xor(ps2, msk);
                ps3 += __shfl_xor(ps3, msk);
            }
            if (n == 0) {
                int ol = i * 16 + g * 4;
                pool_s[wid][ol + 0] = ps0;
                pool_s[wid][ol + 1] = ps1;
                pool_s[wid][ol + 2] = ps2;
                pool_s[wid][ol + 3] = ps3;
            }
        }
        __syncthreads();
        if (tid < 64) {
            float s = pool_s[0][tid] + pool_s[1][tid] + pool_s[2][tid] + pool_s[3][tid];
            pool_out[((size_t)b * 4 + blockIdx.x) * HID + o0 + tid] = s;
        }
    }
}

// ---------------------------------------------------------------------------
// final: fc on pooled sums (4 t-slices) + MMD reduce.
// ---------------------------------------------------------------------------
__global__ __launch_bounds__(256) void final_kernel(
    const float* __restrict__ pp, const float* __restrict__ fcw,
    const float* __restrict__ fcb, const float* __restrict__ partials,
    float* __restrict__ dout)
{
    int tid = threadIdx.x;
    if (tid < 128) {
        int b = tid >> 2, k = tid & 3;
        float s = 0.f;
        for (int c = 0; c < HID; ++c) {
            float pc = 0.f;
#pragma unroll
            for (int xs = 0; xs < 4; ++xs) pc += pp[((size_t)b * 4 + xs) * HID + c];
            s += pc * fcw[k * HID + c];
        }
        dout[tid] = fcb[k] + s * (1.f / 1024.f);
    } else if (tid < 192) {
        int lane = tid - 128;
        float s = 0.f;
        for (int j = 0; j < 8; ++j) s += partials[lane + 64 * j];
        for (int off = 32; off; off >>= 1) s += __shfl_down(s, off);
        if (lane == 0) dout[128] = s * (1.f / (32.f * 32.f * 512.f));
    }
}

// ---------------------------------------------------------------------------
extern "C" void kernel_launch(void* const* d_in, const int* in_sizes, int n_in,
                              void* d_out, int out_size, void* d_ws, size_t ws_size,
                              hipStream_t stream)
{
    const float* feat1 = (const float*)d_in[0];
    const float* feat2 = (const float*)d_in[1];
    const float* wq_a = (const float*)d_in[2];
    const float* bq_a = (const float*)d_in[3];
    const float* wk_a = (const float*)d_in[4];
    const float* bk_a = (const float*)d_in[5];
    const float* wv_a = (const float*)d_in[6];
    const float* bv_a = (const float*)d_in[7];
    const float* wq_b = (const float*)d_in[8];
    const float* bq_b = (const float*)d_in[9];
    const float* wk_b = (const float*)d_in[10];
    const float* bk_b = (const float*)d_in[11];
    const float* wv_b = (const float*)d_in[12];
    const float* bv_b = (const float*)d_in[13];
    const float* cw0 = (const float*)d_in[14];
    const float* cb0 = (const float*)d_in[15];
    const float* rw0 = (const float*)d_in[16];
    const float* rb0 = (const float*)d_in[17];
    const float* cw1 = (const float*)d_in[18];
    const float* cb1 = (const float*)d_in[19];
    const float* rw1 = (const float*)d_in[20];
    const float* rb1 = (const float*)d_in[21];
    const float* cw2 = (const float*)d_in[22];
    const float* cb2 = (const float*)d_in[23];
    const float* rw2 = (const float*)d_in[24];
    const float* rb2 = (const float*)d_in[25];
    const float* fcw = (const float*)d_in[26];
    const float* fcb = (const float*)d_in[27];
    float* dout = (float*)d_out;

    // workspace (float offsets):
    //   Qbf @ 0, Kbf @ 1048576, Vt @ 2097152        (bf16)
    //   f1tf @ 3145728 (fp32), f2tf @ 5242880        (fp32)
    //   xbuf @ 7340032 (bf16 [32][1024][128])
    //   wbuf @ 9437184 (tcn bf16 planes), qkvw @ 9764864
    //   poolpart @ 9814016, mmdpart @ 9846784
    //   h_a @ 10485760 (bf16 [32][1024][256])  -- disjoint from f1tf/f2tf so
    //     merged MMD can run concurrently with TCN L1
    //   h_b @ 4194304 (aliases f1tf tail/f2tf/xbuf head; safe: written by L2
    //     after MMD+L1 complete)
    float* ws = (float*)d_ws;
    unsigned short* Qbf = (unsigned short*)ws;
    unsigned short* Kbf = (unsigned short*)(ws + 1048576);
    unsigned short* Vt  = (unsigned short*)(ws + 2097152);
    float* f1tf = ws + 3145728;
    float* f2tf = ws + 5242880;
    unsigned short* xbuf = (unsigned short*)(ws + 7340032);
    unsigned short* wbuf = (unsigned short*)(ws + 9437184);
    unsigned short* wb0 = wbuf;
    unsigned short* wb1 = wbuf + 131072;
    unsigned short* wb2 = wbuf + 393216;
    unsigned short* qkvw = (unsigned short*)(ws + 9764864);
    unsigned short* w3a = qkvw;
    unsigned short* w3b = qkvw + 3 * 16384;
    float* poolpart = ws + 9814016;
    float* mmdpart  = ws + 9846784;
    unsigned short* h_a = (unsigned short*)(ws + 10485760);
    unsigned short* h_b = (unsigned short*)(ws + 4194304);

    prep_qkvw_kernel<<<dim3(384), 256, 0, stream>>>(
        wq_a, wk_a, wv_a, wq_b, wk_b, wv_b, qkvw);

    proj_mfma_kernel<<<dim3(8, 32), 256, 0, stream>>>(
        feat2, 0, 65536LL, feat1, 0, 65536LL, w3a,
        bq_a, bk_a, bv_a, Qbf, Kbf, Vt);
    attn_mfma_kernel<<<dim3(8, 32), 256, 0, stream>>>(
        Qbf, Kbf, Vt, feat1, 65536LL, 512, 1, f1tf, xbuf, 0,
        cw0, rw0, cw1, rw1, cw2, rw2, wb0, wb1, wb2);

    proj_mfma_kernel<<<dim3(8, 32), 256, 0, stream>>>(
        xbuf, 1, (long long)TP * FF, feat2, 0, 65536LL, w3b,
        bq_b, bk_b, bv_b, Qbf, Kbf, Vt);
    // branch-B attn; y==32 plane performs tcn weight prep concurrently
    attn_mfma_kernel<<<dim3(8, 33), 256, 0, stream>>>(
        Qbf, Kbf, Vt, feat2, 65536LL, 512, 1, f2tf, xbuf, 512,
        cw0, rw0, cw1, rw1, cw2, rw2, wb0, wb1, wb2);

    // TCN L1 with merged MMD plane (y==4)
    tcn_mfma_kernel<<<dim3(4, 5, 32), 256, 0, stream>>>(
        xbuf, 128, 1, wb0, cb0, rb0, h_a, nullptr, 0, f1tf, f2tf, mmdpart, 1);
    tcn_mfma_kernel<<<dim3(4, 4, 32), 256, 0, stream>>>(
        h_a, 256, 2, wb1, cb1, rb1, h_b, nullptr, 0, nullptr, nullptr, nullptr, 0);
    tcn_mfma_kernel<<<dim3(4, 4, 32), 256, 0, stream>>>(
        h_b, 256, 4, wb2, cb2, rb2, h_a, poolpart, 1, nullptr, nullptr, nullptr, 0);

    final_kernel<<<dim3(1), 256, 0, stream>>>(poolpart, fcw, fcb, mmdpart, dout);
}

// Round 13
// 173.643 us; speedup vs baseline: 1.6094x; 1.6094x over previous
//
#include <hip/hip_runtime.h>

#define BB 32
#define TT 512
#define FF 128
#define HID 256
#define TP 1024

typedef __attribute__((ext_vector_type(8))) short s16x8;
typedef __attribute__((ext_vector_type(8))) unsigned short u16x8;
typedef __attribute__((ext_vector_type(4))) unsigned short u16x4;
typedef __attribute__((ext_vector_type(4))) float f32x4;

static __device__ __forceinline__ unsigned short f2bf(float f) {
    unsigned u = __builtin_bit_cast(unsigned, f);
    u = (u + 0x7FFFu + ((u >> 16) & 1u)) >> 16;
    return (unsigned short)u;
}
static __device__ __forceinline__ float bf2f(unsigned short b) {
    return __builtin_bit_cast(float, ((unsigned)b) << 16);
}

// ---------------------------------------------------------------------------
// All weight prep in one launch.
// ---------------------------------------------------------------------------
static __device__ __forceinline__ void tcnw_prep(
    int idx, const float* __restrict__ cw, const float* __restrict__ rw,
    unsigned short* __restrict__ out, int Cin)
{
    int p = idx / (256 * Cin);
    int rem = idx - p * 256 * Cin;
    int o = rem / Cin, c = rem - o * Cin;
    float v = (p < 3) ? cw[(o * Cin + c) * 3 + p] : rw[o * Cin + c];
    out[idx] = f2bf(v);
}

__global__ __launch_bounds__(256) void prep_all_kernel(
    const float* __restrict__ wqa, const float* __restrict__ wka,
    const float* __restrict__ wva, const float* __restrict__ wqb,
    const float* __restrict__ wkb, const float* __restrict__ wvb,
    const float* __restrict__ cw0, const float* __restrict__ rw0,
    const float* __restrict__ cw1, const float* __restrict__ rw1,
    const float* __restrict__ cw2, const float* __restrict__ rw2,
    unsigned short* __restrict__ qkvw, unsigned short* __restrict__ wb0,
    unsigned short* __restrict__ wb1, unsigned short* __restrict__ wb2)
{
    int idx = blockIdx.x * 256 + threadIdx.x;
    if (idx < 98304) {
        int p = idx >> 14, rc = idx & 16383;
        const float* srcs[6] = {wqa, wka, wva, wqb, wkb, wvb};
        float v = srcs[p][rc];
        if (p == 0 || p == 3) v *= 0.088388347648318447f;
        qkvw[idx] = f2bf(v);
    } else if (idx < 229376) {
        tcnw_prep(idx - 98304, cw0, rw0, wb0, 128);
    } else if (idx < 491520) {
        tcnw_prep(idx - 229376, cw1, rw1, wb1, 256);
    } else if (idx < 753664) {
        tcnw_prep(idx - 491520, cw2, rw2, wb2, 256);
    }
}

// ---------------------------------------------------------------------------
// QKV projection via MFMA, 64-row t-tiles.  x source modes:
//   mode 0: fp32 [b][128][512] (c-major);  mode 1: bf16 [b][t][128] (t-major)
// grid (8, 32), block 256 = 4 waves.
// ---------------------------------------------------------------------------
__global__ __launch_bounds__(256) void proj_mfma_kernel(
    const void* __restrict__ xq_src, int xq_mode, long long xq_bs,
    const void* __restrict__ xkv_src, int xkv_mode, long long xkv_bs,
    const unsigned short* __restrict__ w3,
    const float* __restrict__ bq, const float* __restrict__ bk,
    const float* __restrict__ bv,
    unsigned short* __restrict__ Qo, unsigned short* __restrict__ Ko,
    unsigned short* __restrict__ Vt)
{
    int t0 = blockIdx.x * 64, b = blockIdx.y;
    __shared__ __align__(16) unsigned short xsq[64 * 136];
    __shared__ __align__(16) unsigned short xskv[64 * 136];
    int tid = threadIdx.x;
    int wid = tid >> 6, lane = tid & 63;
    int n = lane & 15, g = lane >> 4;
    int tsub = (wid & 1) * 16, fh = (wid >> 1) * 64;

    if (xq_mode == 0) {
        const float* s = (const float*)xq_src + (size_t)b * xq_bs;
        for (int l = tid; l < 8192; l += 256) {
            int c = l >> 6, tt = l & 63;
            xsq[tt * 136 + c] = f2bf(s[(size_t)c * TT + t0 + tt]);
        }
    } else {
        const unsigned short* s = (const unsigned short*)xq_src + (size_t)b * xq_bs;
        for (int l = tid; l < 1024; l += 256) {
            int r = l >> 4, cc = l & 15;
            *(u16x8*)&xsq[r * 136 + cc * 8] = *(const u16x8*)&s[(size_t)(t0 + r) * FF + cc * 8];
        }
    }
    if (xkv_mode == 0) {
        const float* s = (const float*)xkv_src + (size_t)b * xkv_bs;
        for (int l = tid; l < 8192; l += 256) {
            int c = l >> 6, tt = l & 63;
            xskv[tt * 136 + c] = f2bf(s[(size_t)c * TT + t0 + tt]);
        }
    } else {
        const unsigned short* s = (const unsigned short*)xkv_src + (size_t)b * xkv_bs;
        for (int l = tid; l < 1024; l += 256) {
            int r = l >> 4, cc = l & 15;
            *(u16x8*)&xskv[r * 136 + cc * 8] = *(const u16x8*)&s[(size_t)(t0 + r) * FF + cc * 8];
        }
    }
    __syncthreads();

    f32x4 acc[2][3][4];
#pragma unroll
    for (int tt = 0; tt < 2; ++tt)
#pragma unroll
        for (int p = 0; p < 3; ++p)
#pragma unroll
            for (int i = 0; i < 4; ++i) acc[tt][p][i] = (f32x4){0.f, 0.f, 0.f, 0.f};

#pragma unroll
    for (int kk = 0; kk < 4; ++kk) {
        s16x8 bxq0 = *(const s16x8*)&xsq[(tsub + n) * 136 + kk * 32 + g * 8];
        s16x8 bxq1 = *(const s16x8*)&xsq[(32 + tsub + n) * 136 + kk * 32 + g * 8];
        s16x8 bxk0 = *(const s16x8*)&xskv[(tsub + n) * 136 + kk * 32 + g * 8];
        s16x8 bxk1 = *(const s16x8*)&xskv[(32 + tsub + n) * 136 + kk * 32 + g * 8];
#pragma unroll
        for (int i = 0; i < 4; ++i) {
            const unsigned short* wb = &w3[(size_t)(fh + i * 16 + n) * 128 + kk * 32 + g * 8];
            s16x8 a0 = *(const s16x8*)&wb[0];
            s16x8 a1 = *(const s16x8*)&wb[16384];
            s16x8 a2 = *(const s16x8*)&wb[32768];
            acc[0][0][i] = __builtin_amdgcn_mfma_f32_16x16x32_bf16(a0, bxq0, acc[0][0][i], 0, 0, 0);
            acc[0][1][i] = __builtin_amdgcn_mfma_f32_16x16x32_bf16(a1, bxk0, acc[0][1][i], 0, 0, 0);
            acc[0][2][i] = __builtin_amdgcn_mfma_f32_16x16x32_bf16(a2, bxk0, acc[0][2][i], 0, 0, 0);
            acc[1][0][i] = __builtin_amdgcn_mfma_f32_16x16x32_bf16(a0, bxq1, acc[1][0][i], 0, 0, 0);
            acc[1][1][i] = __builtin_amdgcn_mfma_f32_16x16x32_bf16(a1, bxk1, acc[1][1][i], 0, 0, 0);
            acc[1][2][i] = __builtin_amdgcn_mfma_f32_16x16x32_bf16(a2, bxk1, acc[1][2][i], 0, 0, 0);
        }
    }

    const float scale = 0.088388347648318447f;
#pragma unroll
    for (int tt = 0; tt < 2; ++tt) {
        int t = t0 + tt * 32 + tsub + n;
#pragma unroll
        for (int i = 0; i < 4; ++i) {
            int fb = fh + i * 16 + g * 4;
            u16x4 pk;
#pragma unroll
            for (int r = 0; r < 4; ++r) pk[r] = f2bf(acc[tt][0][i][r] + bq[fb + r] * scale);
            *(u16x4*)&Qo[((size_t)b * TT + t) * FF + fb] = pk;
#pragma unroll
            for (int r = 0; r < 4; ++r) pk[r] = f2bf(acc[tt][1][i][r] + bk[fb + r]);
            *(u16x4*)&Ko[((size_t)b * TT + t) * FF + fb] = pk;
#pragma unroll
            for (int r = 0; r < 4; ++r)
                Vt[((size_t)b * FF + fb + r) * TT + t] = f2bf(acc[tt][2][i][r] + bv[fb + r]);
        }
    }
}

// ---------------------------------------------------------------------------
// Flash attention via MFMA.  grid (8, 32), block 256 = 4 waves.
// ---------------------------------------------------------------------------
__global__ __launch_bounds__(256) void attn_mfma_kernel(
    const unsigned short* __restrict__ Qb, const unsigned short* __restrict__ Kb,
    const unsigned short* __restrict__ Vtb,
    const float* __restrict__ orig, long long bso, int cso, int tso,
    float* __restrict__ out_tf, unsigned short* __restrict__ out_x, int xoff)
{
    __shared__ __align__(16) unsigned short Ks[64 * 136];
    __shared__ __align__(16) unsigned short Vs[128 * 72];
    __shared__ __align__(16) unsigned short Ps[4 * 16 * 68];

    int t0 = blockIdx.x * 64, b = blockIdx.y;
    int tid = threadIdx.x;
    int wid = tid >> 6, lane = tid & 63;
    int n = lane & 15, g = lane >> 4;
    int q0 = t0 + wid * 16;
    unsigned short* Pw = &Ps[wid * 1088];

    s16x8 qf[4];
#pragma unroll
    for (int kk = 0; kk < 4; ++kk)
        qf[kk] = *(const s16x8*)&Qb[((size_t)b * TT + q0 + n) * FF + kk * 32 + g * 8];

    u16x8 kst[4], vst[4];
#pragma unroll
    for (int ii = 0; ii < 4; ++ii) {
        int l = tid + 256 * ii;
        kst[ii] = *(const u16x8*)&Kb[((size_t)b * TT + (l >> 4)) * FF + (l & 15) * 8];
        vst[ii] = *(const u16x8*)&Vtb[((size_t)b * FF + (l >> 3)) * TT + (l & 7) * 8];
    }

    f32x4 O[8];
#pragma unroll
    for (int ft = 0; ft < 8; ++ft) O[ft] = (f32x4){0.f, 0.f, 0.f, 0.f};
    float m[4] = {-1e30f, -1e30f, -1e30f, -1e30f};
    float lsum[4] = {0.f, 0.f, 0.f, 0.f};

    for (int it = 0; it < 8; ++it) {
        __syncthreads();
#pragma unroll
        for (int ii = 0; ii < 4; ++ii) {
            int l = tid + 256 * ii;
            *(u16x8*)&Ks[(l >> 4) * 136 + (l & 15) * 8] = kst[ii];
            *(u16x8*)&Vs[(l >> 3) * 72 + (l & 7) * 8] = vst[ii];
        }
        __syncthreads();
        if (it < 7) {
            int s0n = (it + 1) * 64;
#pragma unroll
            for (int ii = 0; ii < 4; ++ii) {
                int l = tid + 256 * ii;
                kst[ii] = *(const u16x8*)&Kb[((size_t)b * TT + s0n + (l >> 4)) * FF + (l & 15) * 8];
                vst[ii] = *(const u16x8*)&Vtb[((size_t)b * FF + (l >> 3)) * TT + s0n + (l & 7) * 8];
            }
        }

        f32x4 acc[4];
#pragma unroll
        for (int st = 0; st < 4; ++st) acc[st] = (f32x4){0.f, 0.f, 0.f, 0.f};
        __builtin_amdgcn_s_setprio(1);
#pragma unroll
        for (int kk = 0; kk < 4; ++kk) {
#pragma unroll
            for (int st = 0; st < 4; ++st) {
                s16x8 kf = *(const s16x8*)&Ks[(st * 16 + n) * 136 + kk * 32 + g * 8];
                acc[st] = __builtin_amdgcn_mfma_f32_16x16x32_bf16(qf[kk], kf, acc[st], 0, 0, 0);
            }
        }
        __builtin_amdgcn_s_setprio(0);

        float mnew[4], c[4], rs[4];
#pragma unroll
        for (int r = 0; r < 4; ++r) {
            float tm = fmaxf(fmaxf(acc[0][r], acc[1][r]), fmaxf(acc[2][r], acc[3][r]));
#pragma unroll
            for (int msk = 1; msk < 16; msk <<= 1) tm = fmaxf(tm, __shfl_xor(tm, msk));
            mnew[r] = fmaxf(m[r], tm);
            c[r] = __expf(m[r] - mnew[r]);
            m[r] = mnew[r];
            rs[r] = 0.f;
        }
#pragma unroll
        for (int st = 0; st < 4; ++st) {
#pragma unroll
            for (int r = 0; r < 4; ++r) {
                float p = __expf(acc[st][r] - mnew[r]);
                rs[r] += p;
                Pw[(g * 4 + r) * 68 + st * 16 + n] = f2bf(p);
            }
        }
#pragma unroll
        for (int r = 0; r < 4; ++r) {
#pragma unroll
            for (int msk = 1; msk < 16; msk <<= 1) rs[r] += __shfl_xor(rs[r], msk);
            lsum[r] = lsum[r] * c[r] + rs[r];
        }
#pragma unroll
        for (int ft = 0; ft < 8; ++ft) {
#pragma unroll
            for (int r = 0; r < 4; ++r) O[ft][r] *= c[r];
        }

        __builtin_amdgcn_s_setprio(1);
#pragma unroll
        for (int ks = 0; ks < 2; ++ks) {
            s16x8 pf = *(const s16x8*)&Pw[n * 68 + ks * 32 + g * 8];
#pragma unroll
            for (int ft = 0; ft < 8; ++ft) {
                s16x8 vf = *(const s16x8*)&Vs[(ft * 16 + n) * 72 + ks * 32 + g * 8];
                O[ft] = __builtin_amdgcn_mfma_f32_16x16x32_bf16(pf, vf, O[ft], 0, 0, 0);
            }
        }
        __builtin_amdgcn_s_setprio(0);
    }

    float rinv[4];
#pragma unroll
    for (int r = 0; r < 4; ++r) rinv[r] = 1.f / lsum[r];
#pragma unroll
    for (int ft = 0; ft < 8; ++ft) {
        int f = ft * 16 + n;
#pragma unroll
        for (int r = 0; r < 4; ++r) {
            int q = q0 + g * 4 + r;
            float val = O[ft][r] * rinv[r];
            float xv = orig[bso * b + (size_t)f * cso + (size_t)q * tso];
            float res = val * xv + xv;
            out_tf[((size_t)b * TT + q) * FF + f] = res;
            out_x[((size_t)b * TP + xoff + q) * FF + f] = f2bf(res);
        }
    }
}

// ---------------------------------------------------------------------------
// MMD partials per timepoint via split-precision MFMA Gram matrices.
// ---------------------------------------------------------------------------
__global__ __launch_bounds__(256) void mmd_kernel(
    const float* __restrict__ f1, const float* __restrict__ f2,
    float* __restrict__ partials)
{
    int t = blockIdx.x;
    __shared__ __align__(16) unsigned short X1h[32 * 136], X1l[32 * 136];
    __shared__ __align__(16) unsigned short X2h[32 * 136], X2l[32 * 136];
    __shared__ float Gs[3][32][33];
    __shared__ float red[256];
    int tid = threadIdx.x;

    for (int l = tid; l < 4096; l += 256) {
        int i = l >> 7, f = l & 127;
        float v1 = f1[((size_t)i * TT + t) * FF + f];
        float v2 = f2[((size_t)i * TT + t) * FF + f];
        unsigned short h1 = f2bf(v1);
        unsigned short h2 = f2bf(v2);
        X1h[i * 136 + f] = h1;
        X1l[i * 136 + f] = f2bf(v1 - bf2f(h1));
        X2h[i * 136 + f] = h2;
        X2l[i * 136 + f] = f2bf(v2 - bf2f(h2));
    }
    __syncthreads();

    int wid = tid >> 6, lane = tid & 63;
    int n = lane & 15, g = lane >> 4;
#pragma unroll
    for (int uu = 0; uu < 3; ++uu) {
        int u = wid * 3 + uu;
        int gram = u >> 2, quad = u & 3;
        int qi = quad >> 1, qj = quad & 1;
        const unsigned short* Ah = (gram == 1) ? X2h : X1h;
        const unsigned short* Al = (gram == 1) ? X2l : X1l;
        const unsigned short* Bh = (gram == 0) ? X1h : X2h;
        const unsigned short* Bl = (gram == 0) ? X1l : X2l;
        f32x4 acc = (f32x4){0.f, 0.f, 0.f, 0.f};
#pragma unroll
        for (int kk = 0; kk < 4; ++kk) {
            int ao = (qi * 16 + n) * 136 + kk * 32 + g * 8;
            int bo = (qj * 16 + n) * 136 + kk * 32 + g * 8;
            s16x8 ah = *(const s16x8*)&Ah[ao];
            s16x8 al = *(const s16x8*)&Al[ao];
            s16x8 bh = *(const s16x8*)&Bh[bo];
            s16x8 bl = *(const s16x8*)&Bl[bo];
            acc = __builtin_amdgcn_mfma_f32_16x16x32_bf16(ah, bh, acc, 0, 0, 0);
            acc = __builtin_amdgcn_mfma_f32_16x16x32_bf16(ah, bl, acc, 0, 0, 0);
            acc = __builtin_amdgcn_mfma_f32_16x16x32_bf16(al, bh, acc, 0, 0, 0);
        }
#pragma unroll
        for (int r = 0; r < 4; ++r)
            Gs[gram][qi * 16 + g * 4 + r][qj * 16 + n] = acc[r];
    }
    __syncthreads();

    float s = 0.f;
#pragma unroll
    for (int r = 0; r < 4; ++r) {
        int p = tid + 256 * r;
        int i = p >> 5, j = p & 31;
        float d11 = Gs[0][i][i] + Gs[0][j][j] - 2.f * Gs[0][i][j];
        float d22 = Gs[1][i][i] + Gs[1][j][j] - 2.f * Gs[1][i][j];
        float d12 = Gs[0][i][i] + Gs[1][j][j] - 2.f * Gs[2][i][j];
        s += __expf(-0.5f * d11) + __expf(-0.5f * d22) - 2.f * __expf(-0.5f * d12);
    }
    red[tid] = s;
    __syncthreads();
    for (int off = 128; off; off >>= 1) {
        if (tid < off) red[tid] += red[tid + off];
        __syncthreads();
    }
    if (tid == 0) partials[t] = red[0];
}

// ---------------------------------------------------------------------------
// TCN layer via MFMA (R11 proven structure): 64o x 64t wave tile, x + w staged
// in LDS load-early/write-late, two barriers per c-slice, setprio on MFMA,
// coalesced output staging via LDS reuse.  grid (4, 4, 32), block 256.
// ---------------------------------------------------------------------------
__global__ __launch_bounds__(256, 2) void tcn_mfma_kernel(
    const unsigned short* __restrict__ x, int Cin, int d,
    const unsigned short* __restrict__ w4,
    const float* __restrict__ cb, const float* __restrict__ rb,
    unsigned short* __restrict__ out, float* __restrict__ pool_out, int do_pool)
{
    int t0 = blockIdx.x * 256, o0 = blockIdx.y * 64, b = blockIdx.z;
    // union: K-loop uses xs (264*40=10560) + wsh (4*64*40=10240) = 20800 u16;
    // epilogue reuses the same memory as ot[256][66] = 16896 u16.
    __shared__ __align__(16) unsigned short smem[20800];
    __shared__ float pool_s[4][64];
    unsigned short* xs = smem;
    unsigned short* wsh = smem + 10560;
    int tid = threadIdx.x;
    int wid = tid >> 6, lane = tid & 63;
    int n = lane & 15, g = lane >> 4;
    int wt = wid * 64;
    int d2 = 2 * d;
    const unsigned short* xb = x + (size_t)b * TP * Cin;

    int gg = tid & 3;
    int xr0 = tid >> 2;
    int tg0 = t0 - d2 + xr0;
    bool xv4 = xr0 < d2;
    const unsigned short* wbase = w4 + (size_t)(o0 + (tid >> 2)) * Cin + gg * 8;
    size_t wps = (size_t)256 * Cin;

    u16x8 sx0, sx1, sx2, sx3, sx4, sw0, sw1, sw2, sw3;
    const u16x8 zz = {0, 0, 0, 0, 0, 0, 0, 0};
#define LDST(C0)                                                               \
    do {                                                                       \
        sx0 = (tg0 >= 0) ? *(const u16x8*)&xb[(size_t)tg0 * Cin + (C0) + gg * 8] : zz; \
        sx1 = *(const u16x8*)&xb[(size_t)(tg0 + 64) * Cin + (C0) + gg * 8];    \
        sx2 = *(const u16x8*)&xb[(size_t)(tg0 + 128) * Cin + (C0) + gg * 8];   \
        sx3 = *(const u16x8*)&xb[(size_t)(tg0 + 192) * Cin + (C0) + gg * 8];   \
        sx4 = xv4 ? *(const u16x8*)&xb[(size_t)(tg0 + 256) * Cin + (C0) + gg * 8] : zz; \
        sw0 = *(const u16x8*)&wbase[(C0)];                                     \
        sw1 = *(const u16x8*)&wbase[wps + (C0)];                               \
        sw2 = *(const u16x8*)&wbase[2 * wps + (C0)];                           \
        sw3 = *(const u16x8*)&wbase[3 * wps + (C0)];                           \
    } while (0)

    f32x4 accc[4][4], accr[4][4];
#pragma unroll
    for (int i = 0; i < 4; ++i)
#pragma unroll
        for (int j = 0; j < 4; ++j) {
            accc[i][j] = (f32x4){0.f, 0.f, 0.f, 0.f};
            accr[i][j] = (f32x4){0.f, 0.f, 0.f, 0.f};
        }

    LDST(0);
    for (int c0 = 0; c0 < Cin; c0 += 32) {
        __syncthreads();
        *(u16x8*)&xs[xr0 * 40 + gg * 8] = sx0;
        *(u16x8*)&xs[(xr0 + 64) * 40 + gg * 8] = sx1;
        *(u16x8*)&xs[(xr0 + 128) * 40 + gg * 8] = sx2;
        *(u16x8*)&xs[(xr0 + 192) * 40 + gg * 8] = sx3;
        if (xv4) *(u16x8*)&xs[(xr0 + 256) * 40 + gg * 8] = sx4;
        {
            int wrow = (tid >> 2) * 40 + gg * 8;
            *(u16x8*)&wsh[wrow] = sw0;
            *(u16x8*)&wsh[2560 + wrow] = sw1;
            *(u16x8*)&wsh[5120 + wrow] = sw2;
            *(u16x8*)&wsh[7680 + wrow] = sw3;
        }
        __syncthreads();
        if (c0 + 32 < Cin) LDST(c0 + 32);

        s16x8 bfr[4][3];
#pragma unroll
        for (int j = 0; j < 4; ++j) {
            int tl = wt + j * 16 + n;
#pragma unroll
            for (int k = 0; k < 3; ++k)
                bfr[j][k] = *(const s16x8*)&xs[(tl + k * d) * 40 + g * 8];
        }
        __builtin_amdgcn_s_setprio(1);
#pragma unroll
        for (int i = 0; i < 4; ++i) {
            int wrow = (i * 16 + n) * 40 + g * 8;
            s16x8 a0 = *(const s16x8*)&wsh[wrow];
            s16x8 a1 = *(const s16x8*)&wsh[2560 + wrow];
            s16x8 a2 = *(const s16x8*)&wsh[5120 + wrow];
            s16x8 ar = *(const s16x8*)&wsh[7680 + wrow];
#pragma unroll
            for (int j = 0; j < 4; ++j) {
                accc[i][j] = __builtin_amdgcn_mfma_f32_16x16x32_bf16(a0, bfr[j][0], accc[i][j], 0, 0, 0);
                accc[i][j] = __builtin_amdgcn_mfma_f32_16x16x32_bf16(a1, bfr[j][1], accc[i][j], 0, 0, 0);
                accc[i][j] = __builtin_amdgcn_mfma_f32_16x16x32_bf16(a2, bfr[j][2], accc[i][j], 0, 0, 0);
                accr[i][j] = __builtin_amdgcn_mfma_f32_16x16x32_bf16(ar, bfr[j][2], accr[i][j], 0, 0, 0);
            }
        }
        __builtin_amdgcn_s_setprio(0);
    }
#undef LDST

    if (!do_pool) {
        // coalesced epilogue: fragments -> ot[256][66] in LDS -> 128B row stores
        __syncthreads();   // all K-loop LDS reads complete before reuse
        unsigned short* ot = smem;
#pragma unroll
        for (int i = 0; i < 4; ++i) {
            int ob = o0 + i * 16 + g * 4;
            float cbv0 = cb[ob], cbv1 = cb[ob + 1], cbv2 = cb[ob + 2], cbv3 = cb[ob + 3];
            float rbv0 = rb[ob], rbv1 = rb[ob + 1], rbv2 = rb[ob + 2], rbv3 = rb[ob + 3];
#pragma unroll
            for (int j = 0; j < 4; ++j) {
                int tl = wt + j * 16 + n;
                u16x4 pk;
                pk[0] = f2bf(fmaxf(accc[i][j][0] + cbv0, 0.f) + accr[i][j][0] + rbv0);
                pk[1] = f2bf(fmaxf(accc[i][j][1] + cbv1, 0.f) + accr[i][j][1] + rbv1);
                pk[2] = f2bf(fmaxf(accc[i][j][2] + cbv2, 0.f) + accr[i][j][2] + rbv2);
                pk[3] = f2bf(fmaxf(accc[i][j][3] + cbv3, 0.f) + accr[i][j][3] + rbv3);
                *(u16x4*)&ot[tl * 66 + i * 16 + g * 4] = pk;
            }
        }
        __syncthreads();
        int tl = tid >> 3, c8 = tid & 7;
#pragma unroll
        for (int s = 0; s < 8; ++s) {
            int trow = tl + 32 * s;
            *(u16x8*)&out[((size_t)b * TP + t0 + trow) * HID + o0 + c8 * 8] =
                *(const u16x8*)&ot[trow * 66 + c8 * 8];
        }
    } else {
        // pooled epilogue (layer 3): reduce sum over t, no h write
#pragma unroll
        for (int i = 0; i < 4; ++i) {
            int ob = o0 + i * 16 + g * 4;
            float cbv0 = cb[ob], cbv1 = cb[ob + 1], cbv2 = cb[ob + 2], cbv3 = cb[ob + 3];
            float rbv0 = rb[ob], rbv1 = rb[ob + 1], rbv2 = rb[ob + 2], rbv3 = rb[ob + 3];
            float ps0 = 0.f, ps1 = 0.f, ps2 = 0.f, ps3 = 0.f;
#pragma unroll
            for (int j = 0; j < 4; ++j) {
                ps0 += fmaxf(accc[i][j][0] + cbv0, 0.f) + accr[i][j][0] + rbv0;
                ps1 += fmaxf(accc[i][j][1] + cbv1, 0.f) + accr[i][j][1] + rbv1;
                ps2 += fmaxf(accc[i][j][2] + cbv2, 0.f) + accr[i][j][2] + rbv2;
                ps3 += fmaxf(accc[i][j][3] + cbv3, 0.f) + accr[i][j][3] + rbv3;
            }
#pragma unroll
            for (int msk = 1; msk < 16; msk <<= 1) {
                ps0 += __shfl_xor(ps0, msk);
                ps1 += __shfl_xor(ps1, msk);
                ps2 += __shfl_xor(ps2, msk);
                ps3 += __shfl_xor(ps3, msk);
            }
            if (n == 0) {
                int ol = i * 16 + g * 4;
                pool_s[wid][ol + 0] = ps0;
                pool_s[wid][ol + 1] = ps1;
                pool_s[wid][ol + 2] = ps2;
                pool_s[wid][ol + 3] = ps3;
            }
        }
        __syncthreads();
        if (tid < 64) {
            float s = pool_s[0][tid] + pool_s[1][tid] + pool_s[2][tid] + pool_s[3][tid];
            pool_out[((size_t)b * 4 + blockIdx.x) * HID + o0 + tid] = s;
        }
    }
}

// ---------------------------------------------------------------------------
// final: fc on pooled sums (4 t-slices) + MMD reduce.
// ---------------------------------------------------------------------------
__global__ __launch_bounds__(256) void final_kernel(
    const float* __restrict__ pp, const float* __restrict__ fcw,
    const float* __restrict__ fcb, const float* __restrict__ partials,
    float* __restrict__ dout)
{
    int tid = threadIdx.x;
    if (tid < 128) {
        int b = tid >> 2, k = tid & 3;
        float s = 0.f;
        for (int c = 0; c < HID; ++c) {
            float pc = 0.f;
#pragma unroll
            for (int xs = 0; xs < 4; ++xs) pc += pp[((size_t)b * 4 + xs) * HID + c];
            s += pc * fcw[k * HID + c];
        }
        dout[tid] = fcb[k] + s * (1.f / 1024.f);
    } else if (tid < 192) {
        int lane = tid - 128;
        float s = 0.f;
        for (int j = 0; j < 8; ++j) s += partials[lane + 64 * j];
        for (int off = 32; off; off >>= 1) s += __shfl_down(s, off);
        if (lane == 0) dout[128] = s * (1.f / (32.f * 32.f * 512.f));
    }
}

// ---------------------------------------------------------------------------
extern "C" void kernel_launch(void* const* d_in, const int* in_sizes, int n_in,
                              void* d_out, int out_size, void* d_ws, size_t ws_size,
                              hipStream_t stream)
{
    const float* feat1 = (const float*)d_in[0];
    const float* feat2 = (const float*)d_in[1];
    const float* wq_a = (const float*)d_in[2];
    const float* bq_a = (const float*)d_in[3];
    const float* wk_a = (const float*)d_in[4];
    const float* bk_a = (const float*)d_in[5];
    const float* wv_a = (const float*)d_in[6];
    const float* bv_a = (const float*)d_in[7];
    const float* wq_b = (const float*)d_in[8];
    const float* bq_b = (const float*)d_in[9];
    const float* wk_b = (const float*)d_in[10];
    const float* bk_b = (const float*)d_in[11];
    const float* wv_b = (const float*)d_in[12];
    const float* bv_b = (const float*)d_in[13];
    const float* cw0 = (const float*)d_in[14];
    const float* cb0 = (const float*)d_in[15];
    const float* rw0 = (const float*)d_in[16];
    const float* rb0 = (const float*)d_in[17];
    const float* cw1 = (const float*)d_in[18];
    const float* cb1 = (const float*)d_in[19];
    const float* rw1 = (const float*)d_in[20];
    const float* rb1 = (const float*)d_in[21];
    const float* cw2 = (const float*)d_in[22];
    const float* cb2 = (const float*)d_in[23];
    const float* rw2 = (const float*)d_in[24];
    const float* rb2 = (const float*)d_in[25];
    const float* fcw = (const float*)d_in[26];
    const float* fcb = (const float*)d_in[27];
    float* dout = (float*)d_out;

    float* ws = (float*)d_ws;
    unsigned short* Qbf = (unsigned short*)ws;
    unsigned short* Kbf = (unsigned short*)(ws + 1048576);
    unsigned short* Vt  = (unsigned short*)(ws + 2097152);
    float* f1tf = ws + 3145728;
    float* f2tf = ws + 5242880;
    unsigned short* xbuf = (unsigned short*)(ws + 7340032);
    unsigned short* wbuf = (unsigned short*)(ws + 9437184);
    unsigned short* wb0 = wbuf;
    unsigned short* wb1 = wbuf + 131072;
    unsigned short* wb2 = wbuf + 393216;
    unsigned short* qkvw = (unsigned short*)(ws + 9764864);
    unsigned short* w3a = qkvw;
    unsigned short* w3b = qkvw + 3 * 16384;
    float* poolpart = ws + 9814016;
    float* mmdpart  = ws + 9846784;
    unsigned short* h_a = (unsigned short*)ws;
    unsigned short* h_b = (unsigned short*)(ws + 4194304);

    prep_all_kernel<<<dim3(2944), 256, 0, stream>>>(
        wq_a, wk_a, wv_a, wq_b, wk_b, wv_b,
        cw0, rw0, cw1, rw1, cw2, rw2, qkvw, wb0, wb1, wb2);

    proj_mfma_kernel<<<dim3(8, 32), 256, 0, stream>>>(
        feat2, 0, 65536LL, feat1, 0, 65536LL, w3a,
        bq_a, bk_a, bv_a, Qbf, Kbf, Vt);
    attn_mfma_kernel<<<dim3(8, 32), 256, 0, stream>>>(
        Qbf, Kbf, Vt, feat1, 65536LL, 512, 1, f1tf, xbuf, 0);

    proj_mfma_kernel<<<dim3(8, 32), 256, 0, stream>>>(
        xbuf, 1, (long long)TP * FF, feat2, 0, 65536LL, w3b,
        bq_b, bk_b, bv_b, Qbf, Kbf, Vt);
    attn_mfma_kernel<<<dim3(8, 32), 256, 0, stream>>>(
        Qbf, Kbf, Vt, feat2, 65536LL, 512, 1, f2tf, xbuf, 512);

    mmd_kernel<<<dim3(512), 256, 0, stream>>>(f1tf, f2tf, mmdpart);

    tcn_mfma_kernel<<<dim3(4, 4, 32), 256, 0, stream>>>(xbuf, 128, 1, wb0, cb0, rb0, h_a, nullptr, 0);
    tcn_mfma_kernel<<<dim3(4, 4, 32), 256, 0, stream>>>(h_a, 256, 2, wb1, cb1, rb1, h_b, nullptr, 0);
    tcn_mfma_kernel<<<dim3(4, 4, 32), 256, 0, stream>>>(h_b, 256, 4, wb2, cb2, rb2, h_a, poolpart, 1);

    final_kernel<<<dim3(1), 256, 0, stream>>>(poolpart, fcw, fcb, mmdpart, dout);
}